// Round 1
// baseline (5824.917 us; speedup 1.0000x reference)
//
#include <hip/hip_runtime.h>
#include <stdint.h>
#include <stddef.h>

// Problem dims
#define Mdim 2048
#define Tdim 64
#define INdim 16
#define Hdim 256
#define Gdim 1024   // 4*H
#define NCdim 64
#define OUTdim 192  // 3*NC
#define RROWS 8
#define NBLK (Mdim / RROWS)  // 256 blocks
#define NTHREADS 512

// ws layout (float offsets)
#define OFF_WIH0T 0                                  // [16][1024]
#define OFF_WHH0T (OFF_WIH0T + INdim * Gdim)         // [256][1024]
#define OFF_WIH1T (OFF_WHH0T + Hdim * Gdim)          // [256][1024]
#define OFF_WHH1T (OFF_WIH1T + Hdim * Gdim)          // [256][1024]
#define OFF_WFCT  (OFF_WHH1T + Hdim * Gdim)          // [256][192]
#define OFF_B0    (OFF_WFCT + Hdim * OUTdim)         // [1024] bih0+bhh0
#define OFF_B1    (OFF_B0 + Gdim)                    // [1024] bih1+bhh1
#define WS_FLOATS (OFF_B1 + Gdim)

#define ROTL32(v, s) (((v) << (s)) | ((v) >> (32 - (s))))

// JAX threefry2x32: 20 rounds, rotations [[13,15,26,6],[17,29,16,24]]
__host__ __device__ inline void tf2x32(uint32_t k0, uint32_t k1, uint32_t x0, uint32_t x1,
                                       uint32_t* o0, uint32_t* o1) {
  uint32_t ks2 = k0 ^ k1 ^ 0x1BD11BDAu;
  x0 += k0; x1 += k1;
  x0 += x1; x1 = ROTL32(x1, 13); x1 ^= x0;
  x0 += x1; x1 = ROTL32(x1, 15); x1 ^= x0;
  x0 += x1; x1 = ROTL32(x1, 26); x1 ^= x0;
  x0 += x1; x1 = ROTL32(x1, 6);  x1 ^= x0;
  x0 += k1; x1 += ks2 + 1u;
  x0 += x1; x1 = ROTL32(x1, 17); x1 ^= x0;
  x0 += x1; x1 = ROTL32(x1, 29); x1 ^= x0;
  x0 += x1; x1 = ROTL32(x1, 16); x1 ^= x0;
  x0 += x1; x1 = ROTL32(x1, 24); x1 ^= x0;
  x0 += ks2; x1 += k0 + 2u;
  x0 += x1; x1 = ROTL32(x1, 13); x1 ^= x0;
  x0 += x1; x1 = ROTL32(x1, 15); x1 ^= x0;
  x0 += x1; x1 = ROTL32(x1, 26); x1 ^= x0;
  x0 += x1; x1 = ROTL32(x1, 6);  x1 ^= x0;
  x0 += k0; x1 += k1 + 3u;
  x0 += x1; x1 = ROTL32(x1, 17); x1 ^= x0;
  x0 += x1; x1 = ROTL32(x1, 29); x1 ^= x0;
  x0 += x1; x1 = ROTL32(x1, 16); x1 ^= x0;
  x0 += x1; x1 = ROTL32(x1, 24); x1 ^= x0;
  x0 += k1; x1 += ks2 + 4u;
  x0 += x1; x1 = ROTL32(x1, 13); x1 ^= x0;
  x0 += x1; x1 = ROTL32(x1, 15); x1 ^= x0;
  x0 += x1; x1 = ROTL32(x1, 26); x1 ^= x0;
  x0 += x1; x1 = ROTL32(x1, 6);  x1 ^= x0;
  x0 += ks2; x1 += k0 + 5u;
  *o0 = x0; *o1 = x1;
}

// JAX partitionable random bits (default since 0.4.30): bits32 = v0 ^ v1 of
// threefry(key, counter_hi=0, counter_lo=flat_index)
__device__ inline uint32_t random_bits32(uint32_t ka, uint32_t kb, uint32_t p) {
  uint32_t a, b;
  tf2x32(ka, kb, 0u, p, &a, &b);
  return a ^ b;
}

__device__ inline float bits_to_u01(uint32_t bits) {
  return __uint_as_float((bits >> 9) | 0x3f800000u) - 1.0f;
}

__device__ inline float sigm(float x) { return 1.0f / (1.0f + expf(-x)); }

// XLA fp32 ErfInv polynomial (Giles)
__device__ inline float erfinv_f32(float x) {
  float w = -log1pf(-x * x);
  float p;
  if (w < 5.0f) {
    w -= 2.5f;
    p = 2.81022636e-08f;
    p = fmaf(p, w, 3.43273939e-07f);
    p = fmaf(p, w, -3.5233877e-06f);
    p = fmaf(p, w, -4.39150654e-06f);
    p = fmaf(p, w, 0.00021858087f);
    p = fmaf(p, w, -0.00125372503f);
    p = fmaf(p, w, -0.00417768164f);
    p = fmaf(p, w, 0.246640727f);
    p = fmaf(p, w, 1.50140941f);
  } else {
    w = sqrtf(w) - 3.0f;
    p = -0.000200214257f;
    p = fmaf(p, w, 0.000100950558f);
    p = fmaf(p, w, 0.00134934322f);
    p = fmaf(p, w, -0.00367342844f);
    p = fmaf(p, w, 0.00573950773f);
    p = fmaf(p, w, -0.0076224613f);
    p = fmaf(p, w, 0.00943887047f);
    p = fmaf(p, w, 1.00167406f);
    p = fmaf(p, w, 2.83297682f);
  }
  return p * x;
}

// Transpose weights into ws ([g][k] -> [k][g]) and fold bias pairs.
__global__ void vfpg_prep_kernel(const float* __restrict__ Wih0, const float* __restrict__ Whh0,
                                 const float* __restrict__ Wih1, const float* __restrict__ Whh1,
                                 const float* __restrict__ fcW, const float* __restrict__ bih0,
                                 const float* __restrict__ bhh0, const float* __restrict__ bih1,
                                 const float* __restrict__ bhh1, float* __restrict__ ws) {
  int i = blockIdx.x * blockDim.x + threadIdx.x;
  int n = blockDim.x * gridDim.x;
  for (int o = i; o < INdim * Gdim; o += n) {
    int f = o / Gdim, g = o % Gdim;
    ws[OFF_WIH0T + o] = Wih0[g * INdim + f];
  }
  for (int o = i; o < Hdim * Gdim; o += n) {
    int k = o / Gdim, g = o % Gdim;
    ws[OFF_WHH0T + o] = Whh0[g * Hdim + k];
    ws[OFF_WIH1T + o] = Wih1[g * Hdim + k];
    ws[OFF_WHH1T + o] = Whh1[g * Hdim + k];
  }
  for (int o = i; o < Hdim * OUTdim; o += n) {
    int k = o / OUTdim, c = o % OUTdim;
    ws[OFF_WFCT + o] = fcW[c * Hdim + k];
  }
  for (int o = i; o < Gdim; o += n) {
    ws[OFF_B0 + o] = bih0[o] + bhh0[o];
    ws[OFF_B1 + o] = bih1[o] + bhh1[o];
  }
}

// Fully fused: both LSTM layers + FC + MDN sampling head. Each block owns
// RROWS=8 rows of M; recurrence is block-local (no grid sync).
__launch_bounds__(NTHREADS, 1)
__global__ void vfpg_lstm_mdn_kernel(const float* __restrict__ z, const float* __restrict__ ws,
                                     const float* __restrict__ fcb, float* __restrict__ out,
                                     uint32_t k1a, uint32_t k1b, uint32_t k2a, uint32_t k2b) {
  __shared__ __align__(16) float h0s[RROWS][Hdim];   // 8 KB
  __shared__ __align__(16) float h1s[RROWS][Hdim];   // 8 KB
  __shared__ __align__(16) float gs[RROWS][Gdim];    // 32 KB
  __shared__ __align__(16) float zs[RROWS][INdim];

  const int tid = threadIdx.x;
  const int m0 = blockIdx.x * RROWS;
  const float* WT_ih0 = ws + OFF_WIH0T;
  const float* WT_hh0 = ws + OFF_WHH0T;
  const float* WT_ih1 = ws + OFF_WIH1T;
  const float* WT_hh1 = ws + OFF_WHH1T;
  const float* WT_fc  = ws + OFF_WFCT;
  const float* B0 = ws + OFF_B0;
  const float* B1 = ws + OFF_B1;

  float c0[RROWS], c1[RROWS];
#pragma unroll
  for (int r = 0; r < RROWS; r++) { c0[r] = 0.0f; c1[r] = 0.0f; }
  for (int i = tid; i < RROWS * Hdim; i += NTHREADS) {
    (&h0s[0][0])[i] = 0.0f;
    (&h1s[0][0])[i] = 0.0f;
  }
  __syncthreads();

  const int g2 = 2 * tid;      // this thread's gate pair
  const int lane = tid & 63;
  const int wid = tid >> 6;

#pragma unroll 1
  for (int t = 0; t < Tdim; t++) {
    // ---- phase 1: stage z[:, t, :] ----
    if (tid < RROWS * INdim) {
      int r = tid >> 4, f = tid & 15;
      zs[r][f] = z[(size_t)(m0 + r) * (Tdim * INdim) + t * INdim + f];
    }
    __syncthreads();

    // ---- phase 2: layer-0 gates = b0 + z*Wih0^T + h0*Whh0^T ----
    {
      float a0[RROWS], a1[RROWS];
      float2 bb = *(const float2*)(B0 + g2);
#pragma unroll
      for (int r = 0; r < RROWS; r++) { a0[r] = bb.x; a1[r] = bb.y; }
#pragma unroll
      for (int f = 0; f < INdim; f++) {
        float2 w = *(const float2*)(WT_ih0 + f * Gdim + g2);
#pragma unroll
        for (int r = 0; r < RROWS; r++) {
          a0[r] += zs[r][f] * w.x;
          a1[r] += zs[r][f] * w.y;
        }
      }
#pragma unroll 2
      for (int k = 0; k < Hdim; k += 4) {
        float2 w0 = *(const float2*)(WT_hh0 + (size_t)(k + 0) * Gdim + g2);
        float2 w1 = *(const float2*)(WT_hh0 + (size_t)(k + 1) * Gdim + g2);
        float2 w2 = *(const float2*)(WT_hh0 + (size_t)(k + 2) * Gdim + g2);
        float2 w3 = *(const float2*)(WT_hh0 + (size_t)(k + 3) * Gdim + g2);
#pragma unroll
        for (int r = 0; r < RROWS; r++) {
          float4 h4 = *(const float4*)&h0s[r][k];
          a0[r] += h4.x * w0.x + h4.y * w1.x + h4.z * w2.x + h4.w * w3.x;
          a1[r] += h4.x * w0.y + h4.y * w1.y + h4.z * w2.y + h4.w * w3.y;
        }
      }
#pragma unroll
      for (int r = 0; r < RROWS; r++) {
        *(float2*)&gs[r][g2] = make_float2(a0[r], a1[r]);
      }
    }
    __syncthreads();

    // ---- phase 3: layer-0 cell/hidden update ----
    if (tid < Hdim) {
      int u = tid;
#pragma unroll
      for (int r = 0; r < RROWS; r++) {
        float gi = gs[r][u], gf = gs[r][Hdim + u];
        float gg = gs[r][2 * Hdim + u], go = gs[r][3 * Hdim + u];
        float cc = sigm(gf) * c0[r] + sigm(gi) * tanhf(gg);
        c0[r] = cc;
        h0s[r][u] = sigm(go) * tanhf(cc);
      }
    }
    __syncthreads();

    // ---- phase 4: layer-1 gates = b1 + h0*Wih1^T + h1*Whh1^T ----
    {
      float a0[RROWS], a1[RROWS];
      float2 bb = *(const float2*)(B1 + g2);
#pragma unroll
      for (int r = 0; r < RROWS; r++) { a0[r] = bb.x; a1[r] = bb.y; }
#pragma unroll 2
      for (int k = 0; k < Hdim; k += 4) {
        float2 u0 = *(const float2*)(WT_ih1 + (size_t)(k + 0) * Gdim + g2);
        float2 u1 = *(const float2*)(WT_ih1 + (size_t)(k + 1) * Gdim + g2);
        float2 u2 = *(const float2*)(WT_ih1 + (size_t)(k + 2) * Gdim + g2);
        float2 u3 = *(const float2*)(WT_ih1 + (size_t)(k + 3) * Gdim + g2);
        float2 v0 = *(const float2*)(WT_hh1 + (size_t)(k + 0) * Gdim + g2);
        float2 v1 = *(const float2*)(WT_hh1 + (size_t)(k + 1) * Gdim + g2);
        float2 v2 = *(const float2*)(WT_hh1 + (size_t)(k + 2) * Gdim + g2);
        float2 v3 = *(const float2*)(WT_hh1 + (size_t)(k + 3) * Gdim + g2);
#pragma unroll
        for (int r = 0; r < RROWS; r++) {
          float4 a4 = *(const float4*)&h0s[r][k];
          float4 b4 = *(const float4*)&h1s[r][k];
          a0[r] += a4.x * u0.x + a4.y * u1.x + a4.z * u2.x + a4.w * u3.x;
          a1[r] += a4.x * u0.y + a4.y * u1.y + a4.z * u2.y + a4.w * u3.y;
          a0[r] += b4.x * v0.x + b4.y * v1.x + b4.z * v2.x + b4.w * v3.x;
          a1[r] += b4.x * v0.y + b4.y * v1.y + b4.z * v2.y + b4.w * v3.y;
        }
      }
#pragma unroll
      for (int r = 0; r < RROWS; r++) {
        *(float2*)&gs[r][g2] = make_float2(a0[r], a1[r]);
      }
    }
    __syncthreads();

    // ---- phase 5: layer-1 cell/hidden update ----
    if (tid < Hdim) {
      int u = tid;
#pragma unroll
      for (int r = 0; r < RROWS; r++) {
        float gi = gs[r][u], gf = gs[r][Hdim + u];
        float gg = gs[r][2 * Hdim + u], go = gs[r][3 * Hdim + u];
        float cc = sigm(gf) * c1[r] + sigm(gi) * tanhf(gg);
        c1[r] = cc;
        h1s[r][u] = sigm(go) * tanhf(cc);
      }
    }
    __syncthreads();

    // ---- phase 6: FC + MDN head; wave w handles row r=w ----
    {
      const int r = wid;
      const int mrow = m0 + r;
      float yg = fcb[lane];           // gamma logit, component c = lane
      float ysg = fcb[64 + lane];     // log-sigma
      float ym = fcb[128 + lane];     // mu
#pragma unroll 2
      for (int k = 0; k < Hdim; k += 4) {
        float4 h4 = *(const float4*)&h1s[r][k];
#pragma unroll
        for (int j = 0; j < 4; j++) {
          const float* Wkj = WT_fc + (size_t)(k + j) * OUTdim;
          float hv = (&h4.x)[j];
          yg  += hv * Wkj[lane];
          ysg += hv * Wkj[64 + lane];
          ym  += hv * Wkj[128 + lane];
        }
      }

      // Gumbel noise for categorical; argmax(g + logit) == argmax(g + log_softmax)
      uint32_t p = ((uint32_t)mrow * Tdim + (uint32_t)t) * NCdim + (uint32_t)lane;
      uint32_t bits = random_bits32(k1a, k1b, p);
      float u01 = bits_to_u01(bits);
      const float tinyf = 1.17549435e-38f;
      float uu = fmaxf(tinyf, u01 + tinyf);
      float gum = -logf(-logf(uu));
      float val = gum + yg;
      int idx = lane;
#pragma unroll
      for (int s = 1; s < 64; s <<= 1) {
        float ov = __shfl_xor(val, s);
        int oi = __shfl_xor(idx, s);
        if (ov > val || (ov == val && oi < idx)) { val = ov; idx = oi; }
      }
      float mu_sel = __shfl(ym, idx);
      float s_sel = __shfl(ysg, idx);

      // normal eps (shape (M,T,1), flat index = mrow*T + t)
      uint32_t p2 = (uint32_t)mrow * Tdim + (uint32_t)t;
      uint32_t ebits = random_bits32(k2a, k2b, p2);
      float ue = bits_to_u01(ebits);
      const float lo = __uint_as_float(0xBF7FFFFFu);  // nextafter(-1, 0)
      float un = fmaxf(lo, ue * 2.0f + lo);
      float eps = 1.41421356f * erfinv_f32(un);

      float x_pred = mu_sel + expf(s_sel) * eps;

      // x_cond_prob = sum_c softmax(yg)_c * exp(-0.5 d^2 - 66 s_c - 32 ln 2pi)
      float mx = yg;
#pragma unroll
      for (int s = 1; s < 64; s <<= 1) mx = fmaxf(mx, __shfl_xor(mx, s));
      float se = expf(yg - mx);
#pragma unroll
      for (int s = 1; s < 64; s <<= 1) se += __shfl_xor(se, s);
      float d = x_pred - ym;
      float lk = -0.5f * d * d - 66.0f * ysg - 58.812066f;
      float ts = expf(yg - mx + lk);
#pragma unroll
      for (int s = 1; s < 64; s <<= 1) ts += __shfl_xor(ts, s);
      float prob = ts / se;

      if (lane == 0) {
        out[(size_t)mrow * Tdim + t] = x_pred;
        out[(size_t)Mdim * Tdim + (size_t)mrow * Tdim + t] = prob;
      }
    }
    __syncthreads();
  }
}

extern "C" void kernel_launch(void* const* d_in, const int* in_sizes, int n_in,
                              void* d_out, int out_size, void* d_ws, size_t ws_size,
                              hipStream_t stream) {
  const float* z    = (const float*)d_in[0];
  const float* Wih0 = (const float*)d_in[1];
  const float* Whh0 = (const float*)d_in[2];
  const float* bih0 = (const float*)d_in[3];
  const float* bhh0 = (const float*)d_in[4];
  const float* Wih1 = (const float*)d_in[5];
  const float* Whh1 = (const float*)d_in[6];
  const float* bih1 = (const float*)d_in[7];
  const float* bhh1 = (const float*)d_in[8];
  const float* fcW  = (const float*)d_in[9];
  const float* fcb  = (const float*)d_in[10];
  float* ws = (float*)d_ws;
  float* out = (float*)d_out;

  if (ws_size < (size_t)WS_FLOATS * sizeof(float)) return;  // need ~3.3 MB scratch

  vfpg_prep_kernel<<<dim3(512), dim3(256), 0, stream>>>(
      Wih0, Whh0, Wih1, Whh1, fcW, bih0, bhh0, bih1, bhh1, ws);

  // keys: jax.random.key(42) = (0,42); fold-like split (partitionable mode)
  uint32_t k1a, k1b, k2a, k2b;
  tf2x32(0u, 42u, 0u, 0u, &k1a, &k1b);
  tf2x32(0u, 42u, 0u, 1u, &k2a, &k2b);

  vfpg_lstm_mdn_kernel<<<dim3(NBLK), dim3(NTHREADS), 0, stream>>>(
      z, ws, fcb, out, k1a, k1b, k2a, k2b);
}

// Round 4
// 5801.229 us; speedup vs baseline: 1.0041x; 1.0041x over previous
//
#include <hip/hip_runtime.h>
#include <stdint.h>
#include <stddef.h>

// Problem dims
#define Mdim 2048
#define Tdim 64
#define INdim 16
#define Hdim 256
#define Gdim 1024   // 4*H
#define NCdim 64
#define OUTdim 192  // 3*NC
#define RROWS 8
#define NBLK (Mdim / RROWS)  // 256 blocks
#define NTHREADS 512

// ws layout (float offsets). Lane-paired gate layout: thread tt -> unit u=tt>>1,
// pair pp=tt&1; gates g1 = pp*512+u, g2 = g1+256  (p=0:{i,f}, p=1:{g,o}).
#define OFF_WZ0P 0                         // [8][512] float4: 2 k's x 2 gates of Wih0
#define OFF_WH0P (OFF_WZ0P + 8 * 512 * 4)  // [128][512] float4: 2 k's x 2 gates of Whh0
#define OFF_W1P  (OFF_WH0P + 128 * 512 * 4) // [256][512] float4: (ih1 g1, ih1 g2, hh1 g1, hh1 g2)
#define OFF_WFC2 (OFF_W1P + 256 * 512 * 4)  // [256][64] float2: (gamma, sigma) cols
#define OFF_WFCM (OFF_WFC2 + 256 * 64 * 2)  // [256][64] float: mu col
#define OFF_BG0  (OFF_WFCM + 256 * 64)      // [512] float2 folded biases layer0
#define OFF_BG1  (OFF_BG0 + 1024)           // [512] float2 folded biases layer1
#define WS_FLOATS (OFF_BG1 + 1024)          // = 854016 floats (same as prior round)

#define ROTL32(v, s) (((v) << (s)) | ((v) >> (32 - (s))))

// JAX threefry2x32: 20 rounds, rotations [[13,15,26,6],[17,29,16,24]]
__host__ __device__ inline void tf2x32(uint32_t k0, uint32_t k1, uint32_t x0, uint32_t x1,
                                       uint32_t* o0, uint32_t* o1) {
  uint32_t ks2 = k0 ^ k1 ^ 0x1BD11BDAu;
  x0 += k0; x1 += k1;
  x0 += x1; x1 = ROTL32(x1, 13); x1 ^= x0;
  x0 += x1; x1 = ROTL32(x1, 15); x1 ^= x0;
  x0 += x1; x1 = ROTL32(x1, 26); x1 ^= x0;
  x0 += x1; x1 = ROTL32(x1, 6);  x1 ^= x0;
  x0 += k1; x1 += ks2 + 1u;
  x0 += x1; x1 = ROTL32(x1, 17); x1 ^= x0;
  x0 += x1; x1 = ROTL32(x1, 29); x1 ^= x0;
  x0 += x1; x1 = ROTL32(x1, 16); x1 ^= x0;
  x0 += x1; x1 = ROTL32(x1, 24); x1 ^= x0;
  x0 += ks2; x1 += k0 + 2u;
  x0 += x1; x1 = ROTL32(x1, 13); x1 ^= x0;
  x0 += x1; x1 = ROTL32(x1, 15); x1 ^= x0;
  x0 += x1; x1 = ROTL32(x1, 26); x1 ^= x0;
  x0 += x1; x1 = ROTL32(x1, 6);  x1 ^= x0;
  x0 += k0; x1 += k1 + 3u;
  x0 += x1; x1 = ROTL32(x1, 17); x1 ^= x0;
  x0 += x1; x1 = ROTL32(x1, 29); x1 ^= x0;
  x0 += x1; x1 = ROTL32(x1, 16); x1 ^= x0;
  x0 += x1; x1 = ROTL32(x1, 24); x1 ^= x0;
  x0 += k1; x1 += ks2 + 4u;
  x0 += x1; x1 = ROTL32(x1, 13); x1 ^= x0;
  x0 += x1; x1 = ROTL32(x1, 15); x1 ^= x0;
  x0 += x1; x1 = ROTL32(x1, 26); x1 ^= x0;
  x0 += x1; x1 = ROTL32(x1, 6);  x1 ^= x0;
  x0 += ks2; x1 += k0 + 5u;
  *o0 = x0; *o1 = x1;
}

__device__ inline uint32_t random_bits32(uint32_t ka, uint32_t kb, uint32_t p) {
  uint32_t a, b;
  tf2x32(ka, kb, 0u, p, &a, &b);
  return a ^ b;
}

__device__ inline float bits_to_u01(uint32_t bits) {
  return __uint_as_float((bits >> 9) | 0x3f800000u) - 1.0f;
}

__device__ inline float sigm_fast(float x) { return 1.0f / (1.0f + __expf(-x)); }

// XLA fp32 ErfInv polynomial
__device__ inline float erfinv_f32(float x) {
  float w = -log1pf(-x * x);
  float p;
  if (w < 5.0f) {
    w -= 2.5f;
    p = 2.81022636e-08f;
    p = fmaf(p, w, 3.43273939e-07f);
    p = fmaf(p, w, -3.5233877e-06f);
    p = fmaf(p, w, -4.39150654e-06f);
    p = fmaf(p, w, 0.00021858087f);
    p = fmaf(p, w, -0.00125372503f);
    p = fmaf(p, w, -0.00417768164f);
    p = fmaf(p, w, 0.246640727f);
    p = fmaf(p, w, 1.50140941f);
  } else {
    w = sqrtf(w) - 3.0f;
    p = -0.000200214257f;
    p = fmaf(p, w, 0.000100950558f);
    p = fmaf(p, w, 0.00134934322f);
    p = fmaf(p, w, -0.00367342844f);
    p = fmaf(p, w, 0.00573950773f);
    p = fmaf(p, w, -0.0076224613f);
    p = fmaf(p, w, 0.00943887047f);
    p = fmaf(p, w, 1.00167406f);
    p = fmaf(p, w, 2.83297682f);
  }
  return p * x;
}

__global__ void vfpg_prep(const float* __restrict__ Wih0, const float* __restrict__ Whh0,
                          const float* __restrict__ Wih1, const float* __restrict__ Whh1,
                          const float* __restrict__ fcW, const float* __restrict__ bih0,
                          const float* __restrict__ bhh0, const float* __restrict__ bih1,
                          const float* __restrict__ bhh1, float* __restrict__ ws) {
  int i0 = blockIdx.x * blockDim.x + threadIdx.x;
  int n = blockDim.x * gridDim.x;
  float4* wz = (float4*)(ws + OFF_WZ0P);
  for (int o = i0; o < 8 * 512; o += n) {
    int kz = o >> 9, tt = o & 511, uu = tt >> 1, pp = tt & 1;
    int g1 = pp * 512 + uu, g2 = g1 + 256;
    wz[o] = make_float4(Wih0[g1 * INdim + 2 * kz], Wih0[g2 * INdim + 2 * kz],
                        Wih0[g1 * INdim + 2 * kz + 1], Wih0[g2 * INdim + 2 * kz + 1]);
  }
  float4* wh = (float4*)(ws + OFF_WH0P);
  for (int o = i0; o < 128 * 512; o += n) {
    int k2 = o >> 9, tt = o & 511, uu = tt >> 1, pp = tt & 1;
    int g1 = pp * 512 + uu, g2 = g1 + 256;
    wh[o] = make_float4(Whh0[g1 * Hdim + 2 * k2], Whh0[g2 * Hdim + 2 * k2],
                        Whh0[g1 * Hdim + 2 * k2 + 1], Whh0[g2 * Hdim + 2 * k2 + 1]);
  }
  float4* w1 = (float4*)(ws + OFF_W1P);
  for (int o = i0; o < 256 * 512; o += n) {
    int k = o >> 9, tt = o & 511, uu = tt >> 1, pp = tt & 1;
    int g1 = pp * 512 + uu, g2 = g1 + 256;
    w1[o] = make_float4(Wih1[g1 * Hdim + k], Wih1[g2 * Hdim + k],
                        Whh1[g1 * Hdim + k], Whh1[g2 * Hdim + k]);
  }
  float2* wfc2 = (float2*)(ws + OFF_WFC2);
  for (int o = i0; o < 256 * 64; o += n) {
    int k = o >> 6, c = o & 63;
    wfc2[o] = make_float2(fcW[c * Hdim + k], fcW[(64 + c) * Hdim + k]);
    ws[OFF_WFCM + o] = fcW[(128 + c) * Hdim + k];
  }
  float2* b0 = (float2*)(ws + OFF_BG0);
  float2* b1 = (float2*)(ws + OFF_BG1);
  for (int o = i0; o < 512; o += n) {
    int uu = o >> 1, pp = o & 1;
    int g1 = pp * 512 + uu, g2 = g1 + 256;
    b0[o] = make_float2(bih0[g1] + bhh0[g1], bih0[g2] + bhh0[g2]);
    b1[o] = make_float2(bih1[g1] + bhh1[g1], bih1[g2] + bhh1[g2]);
  }
}

__launch_bounds__(NTHREADS, 1)
__global__ void vfpg_fused(const float* __restrict__ z, const float* __restrict__ ws,
                           const float* __restrict__ fcb, float* __restrict__ out,
                           uint32_t k1a, uint32_t k1b, uint32_t k2a, uint32_t k2b) {
  __shared__ __align__(16) float h0s[2][RROWS][Hdim];  // 16 KB
  __shared__ __align__(16) float h1s[2][RROWS][Hdim];  // 16 KB
  __shared__ __align__(16) float zsb[2][RROWS][INdim]; // 1 KB

  const int tid = threadIdx.x;
  const int u = tid >> 1;
  const int p = tid & 1;
  const int lane = tid & 63;
  const int wid = tid >> 6;
  const int m0 = blockIdx.x * RROWS;

  const float4* WZ = (const float4*)(ws + OFF_WZ0P);
  const float4* WH = (const float4*)(ws + OFF_WH0P);
  const float4* W1 = (const float4*)(ws + OFF_W1P);
  const float2* WFC2 = (const float2*)(ws + OFF_WFC2);
  const float* WFCM = ws + OFF_WFCM;
  const float2 bg0 = ((const float2*)(ws + OFF_BG0))[tid];
  const float2 bg1 = ((const float2*)(ws + OFF_BG1))[tid];
  const float fbg = fcb[lane], fbs = fcb[64 + lane], fbm = fcb[128 + lane];

  float c0[4] = {0.f, 0.f, 0.f, 0.f};
  float c1[4] = {0.f, 0.f, 0.f, 0.f};

  for (int i = tid; i < RROWS * Hdim; i += NTHREADS) {
    (&h0s[1][0][0])[i] = 0.0f;
    (&h1s[1][0][0])[i] = 0.0f;
  }
  if (tid < RROWS * INdim) {
    int r = tid >> 4, f = tid & 15;
    zsb[0][r][f] = z[(size_t)(m0 + r) * (Tdim * INdim) + f];
  }
  __syncthreads();

#pragma unroll 1
  for (int t = 0; t < Tdim; t++) {
    const int cur = t & 1, prv = cur ^ 1;

    // ============ Phase A: layer-0 gates + cell update ============
    {
      float a[8], b[8];
#pragma unroll
      for (int r = 0; r < 8; r++) { a[r] = bg0.x; b[r] = bg0.y; }
#pragma unroll
      for (int kz = 0; kz < 8; kz++) {
        float4 w = WZ[kz * 512 + tid];
#pragma unroll
        for (int r = 0; r < 8; r++) {
          float2 zz = *(const float2*)&zsb[cur][r][2 * kz];
          a[r] = fmaf(zz.x, w.x, fmaf(zz.y, w.z, a[r]));
          b[r] = fmaf(zz.x, w.y, fmaf(zz.y, w.w, b[r]));
        }
      }
#pragma unroll 2
      for (int k4 = 0; k4 < 64; k4++) {
        float4 w0 = WH[(2 * k4 + 0) * 512 + tid];
        float4 w1v = WH[(2 * k4 + 1) * 512 + tid];
#pragma unroll
        for (int r = 0; r < 8; r++) {
          float4 h4 = *(const float4*)&h0s[prv][r][4 * k4];
          a[r] += h4.x * w0.x + h4.y * w0.z + h4.z * w1v.x + h4.w * w1v.z;
          b[r] += h4.x * w0.y + h4.y * w0.w + h4.z * w1v.y + h4.w * w1v.w;
        }
      }
      // update: p=0 holds (i,f), p=1 holds (g,o). tanh(x) = 2*sigm(2x)-1.
      float sa[8], sb[8];
#pragma unroll
      for (int r = 0; r < 8; r++) {
        float xa = p ? 2.0f * a[r] : a[r];
        float s = sigm_fast(xa);
        sa[r] = p ? fmaf(2.0f, s, -1.0f) : s;
        sb[r] = sigm_fast(b[r]);
      }
#pragma unroll
      for (int j = 0; j < 4; j++) {
        float s1 = __shfl_xor(p ? sa[j] : sa[j + 4], 1);
        float s2 = __shfl_xor(p ? sb[j] : sb[j + 4], 1);
        float own_a = p ? sa[j + 4] : sa[j];
        float own_b = p ? sb[j + 4] : sb[j];
        float si = p ? s1 : own_a;
        float sf = p ? s2 : own_b;
        float tg = p ? own_a : s1;
        float so = p ? own_b : s2;
        c0[j] = sf * c0[j] + si * tg;
        float th = fmaf(2.0f, sigm_fast(2.0f * c0[j]), -1.0f);
        h0s[cur][p * 4 + j][u] = so * th;
      }
    }
    __syncthreads();

    // ============ Phase B: layer-1 gates + cell update ============
    {
      float a[8], b[8];
#pragma unroll
      for (int r = 0; r < 8; r++) { a[r] = bg1.x; b[r] = bg1.y; }
#pragma unroll 2
      for (int k4 = 0; k4 < 64; k4++) {
        float4 w0 = W1[(4 * k4 + 0) * 512 + tid];
        float4 w1v = W1[(4 * k4 + 1) * 512 + tid];
        float4 w2 = W1[(4 * k4 + 2) * 512 + tid];
        float4 w3 = W1[(4 * k4 + 3) * 512 + tid];
#pragma unroll
        for (int r = 0; r < 8; r++) {
          float4 x = *(const float4*)&h0s[cur][r][4 * k4];
          float4 y = *(const float4*)&h1s[prv][r][4 * k4];
          a[r] += x.x * w0.x + x.y * w1v.x + x.z * w2.x + x.w * w3.x
                + y.x * w0.z + y.y * w1v.z + y.z * w2.z + y.w * w3.z;
          b[r] += x.x * w0.y + x.y * w1v.y + x.z * w2.y + x.w * w3.y
                + y.x * w0.w + y.y * w1v.w + y.z * w2.w + y.w * w3.w;
        }
      }
      float sa[8], sb[8];
#pragma unroll
      for (int r = 0; r < 8; r++) {
        float xa = p ? 2.0f * a[r] : a[r];
        float s = sigm_fast(xa);
        sa[r] = p ? fmaf(2.0f, s, -1.0f) : s;
        sb[r] = sigm_fast(b[r]);
      }
#pragma unroll
      for (int j = 0; j < 4; j++) {
        float s1 = __shfl_xor(p ? sa[j] : sa[j + 4], 1);
        float s2 = __shfl_xor(p ? sb[j] : sb[j + 4], 1);
        float own_a = p ? sa[j + 4] : sa[j];
        float own_b = p ? sb[j + 4] : sb[j];
        float si = p ? s1 : own_a;
        float sf = p ? s2 : own_b;
        float tg = p ? own_a : s1;
        float so = p ? own_b : s2;
        c1[j] = sf * c1[j] + si * tg;
        float th = fmaf(2.0f, sigm_fast(2.0f * c1[j]), -1.0f);
        h1s[cur][p * 4 + j][u] = so * th;
      }
    }
    __syncthreads();

    // ============ Phase C: FC + MDN head (wave w -> row w) + z stage ============
    {
      if (t + 1 < Tdim && tid < RROWS * INdim) {
        int r = tid >> 4, f = tid & 15;
        zsb[prv][r][f] = z[(size_t)(m0 + r) * (Tdim * INdim) + (t + 1) * INdim + f];
      }
      const int r = wid;
      const int mrow = m0 + r;
      float yg = fbg, ysg = fbs, ym = fbm;
#pragma unroll 2
      for (int k4 = 0; k4 < 64; k4++) {
        float4 h4 = *(const float4*)&h1s[cur][r][4 * k4];
#pragma unroll
        for (int j = 0; j < 4; j++) {
          int k = 4 * k4 + j;
          float2 wgs = WFC2[k * 64 + lane];
          float wm = WFCM[k * 64 + lane];
          float hv = (&h4.x)[j];
          yg = fmaf(hv, wgs.x, yg);
          ysg = fmaf(hv, wgs.y, ysg);
          ym = fmaf(hv, wm, ym);
        }
      }

      // Gumbel-argmax categorical
      uint32_t pp = ((uint32_t)mrow * Tdim + (uint32_t)t) * NCdim + (uint32_t)lane;
      uint32_t bits = random_bits32(k1a, k1b, pp);
      float u01 = bits_to_u01(bits);
      const float tinyf = 1.17549435e-38f;
      float uu = fmaxf(tinyf, u01 + tinyf);
      float gum = -logf(-logf(uu));
      float val = gum + yg;
      int idx = lane;
#pragma unroll
      for (int s = 1; s < 64; s <<= 1) {
        float ov = __shfl_xor(val, s);
        int oi = __shfl_xor(idx, s);
        if (ov > val || (ov == val && oi < idx)) { val = ov; idx = oi; }
      }
      float mu_sel = __shfl(ym, idx);
      float s_sel = __shfl(ysg, idx);

      uint32_t p2 = (uint32_t)mrow * Tdim + (uint32_t)t;
      uint32_t ebits = random_bits32(k2a, k2b, p2);
      float ue = bits_to_u01(ebits);
      const float lo = __uint_as_float(0xBF7FFFFFu);  // nextafter(-1, 0)
      float un = fmaxf(lo, ue * 2.0f + lo);
      float eps = 1.41421356f * erfinv_f32(un);

      float x_pred = mu_sel + expf(s_sel) * eps;

      // x_cond_prob in log domain
      float mx = yg;
#pragma unroll
      for (int s = 1; s < 64; s <<= 1) mx = fmaxf(mx, __shfl_xor(mx, s));
      float se = expf(yg - mx);
#pragma unroll
      for (int s = 1; s < 64; s <<= 1) se += __shfl_xor(se, s);
      float d = x_pred - ym;
      float lk = -0.5f * d * d - 66.0f * ysg - 58.812066f;
      float ts = expf(yg - mx + lk);
#pragma unroll
      for (int s = 1; s < 64; s <<= 1) ts += __shfl_xor(ts, s);
      float prob = ts / se;

      if (lane == 0) {
        out[(size_t)mrow * Tdim + t] = x_pred;
        out[(size_t)Mdim * Tdim + (size_t)mrow * Tdim + t] = prob;
      }
    }
    __syncthreads();
  }
}

extern "C" void kernel_launch(void* const* d_in, const int* in_sizes, int n_in,
                              void* d_out, int out_size, void* d_ws, size_t ws_size,
                              hipStream_t stream) {
  const float* z    = (const float*)d_in[0];
  const float* Wih0 = (const float*)d_in[1];
  const float* Whh0 = (const float*)d_in[2];
  const float* bih0 = (const float*)d_in[3];
  const float* bhh0 = (const float*)d_in[4];
  const float* Wih1 = (const float*)d_in[5];
  const float* Whh1 = (const float*)d_in[6];
  const float* bih1 = (const float*)d_in[7];
  const float* bhh1 = (const float*)d_in[8];
  const float* fcW  = (const float*)d_in[9];
  const float* fcb  = (const float*)d_in[10];
  float* ws = (float*)d_ws;
  float* out = (float*)d_out;

  if (ws_size < (size_t)WS_FLOATS * sizeof(float)) return;

  vfpg_prep<<<dim3(512), dim3(256), 0, stream>>>(
      Wih0, Whh0, Wih1, Whh1, fcW, bih0, bhh0, bih1, bhh1, ws);

  uint32_t k1a, k1b, k2a, k2b;
  tf2x32(0u, 42u, 0u, 0u, &k1a, &k1b);
  tf2x32(0u, 42u, 0u, 1u, &k2a, &k2b);

  vfpg_fused<<<dim3(NBLK), dim3(NTHREADS), 0, stream>>>(
      z, ws, fcb, out, k1a, k1b, k2a, k2b);
}

// Round 5
// 5423.874 us; speedup vs baseline: 1.0739x; 1.0696x over previous
//
#include <hip/hip_runtime.h>
#include <stdint.h>
#include <stddef.h>

// Problem dims
#define Mdim 2048
#define Tdim 64
#define INdim 16
#define Hdim 256
#define Gdim 1024   // 4*H
#define NCdim 64
#define OUTdim 192  // 3*NC
#define RROWS 8
#define NBLK (Mdim / RROWS)  // 256 blocks
#define NTHREADS 512

// ws layout (float offsets). Lane-paired gate layout: thread tt -> unit u=tt>>1,
// pair pp=tt&1; gates g1 = pp*512+u, g2 = g1+256  (p=0:{i,f}, p=1:{g,o}).
#define OFF_WZ0P 0                           // [8][512] float4
#define OFF_WH0P (OFF_WZ0P + 8 * 512 * 4)    // [128][512] float4
#define OFF_W1P  (OFF_WH0P + 128 * 512 * 4)  // [256][512] float4
#define OFF_WFCP (OFF_W1P + 256 * 512 * 4)   // [256][64] float4 {g,s,m,0}
#define OFF_BG0  (OFF_WFCP + 256 * 64 * 4)   // [512] float2
#define OFF_BG1  (OFF_BG0 + 1024)            // [512] float2
#define WS_FUSED (OFF_BG1 + 1024)            // 870400 floats = 3.48 MB
#define OFF_H1   WS_FUSED                    // [M*T][256] fp32 h1 (SPLIT only)
#define WS_SPLIT (OFF_H1 + Mdim * Tdim * Hdim)  // 34,424,832 floats = 137.7 MB

#define ROTL32(v, s) (((v) << (s)) | ((v) >> (32 - (s))))

// JAX threefry2x32: 20 rounds, rotations [[13,15,26,6],[17,29,16,24]]
__host__ __device__ inline void tf2x32(uint32_t k0, uint32_t k1, uint32_t x0, uint32_t x1,
                                       uint32_t* o0, uint32_t* o1) {
  uint32_t ks2 = k0 ^ k1 ^ 0x1BD11BDAu;
  x0 += k0; x1 += k1;
  x0 += x1; x1 = ROTL32(x1, 13); x1 ^= x0;
  x0 += x1; x1 = ROTL32(x1, 15); x1 ^= x0;
  x0 += x1; x1 = ROTL32(x1, 26); x1 ^= x0;
  x0 += x1; x1 = ROTL32(x1, 6);  x1 ^= x0;
  x0 += k1; x1 += ks2 + 1u;
  x0 += x1; x1 = ROTL32(x1, 17); x1 ^= x0;
  x0 += x1; x1 = ROTL32(x1, 29); x1 ^= x0;
  x0 += x1; x1 = ROTL32(x1, 16); x1 ^= x0;
  x0 += x1; x1 = ROTL32(x1, 24); x1 ^= x0;
  x0 += ks2; x1 += k0 + 2u;
  x0 += x1; x1 = ROTL32(x1, 13); x1 ^= x0;
  x0 += x1; x1 = ROTL32(x1, 15); x1 ^= x0;
  x0 += x1; x1 = ROTL32(x1, 26); x1 ^= x0;
  x0 += x1; x1 = ROTL32(x1, 6);  x1 ^= x0;
  x0 += k0; x1 += k1 + 3u;
  x0 += x1; x1 = ROTL32(x1, 17); x1 ^= x0;
  x0 += x1; x1 = ROTL32(x1, 29); x1 ^= x0;
  x0 += x1; x1 = ROTL32(x1, 16); x1 ^= x0;
  x0 += x1; x1 = ROTL32(x1, 24); x1 ^= x0;
  x0 += k1; x1 += ks2 + 4u;
  x0 += x1; x1 = ROTL32(x1, 13); x1 ^= x0;
  x0 += x1; x1 = ROTL32(x1, 15); x1 ^= x0;
  x0 += x1; x1 = ROTL32(x1, 26); x1 ^= x0;
  x0 += x1; x1 = ROTL32(x1, 6);  x1 ^= x0;
  x0 += ks2; x1 += k0 + 5u;
  *o0 = x0; *o1 = x1;
}

__device__ inline uint32_t random_bits32(uint32_t ka, uint32_t kb, uint32_t p) {
  uint32_t a, b;
  tf2x32(ka, kb, 0u, p, &a, &b);
  return a ^ b;
}

__device__ inline float bits_to_u01(uint32_t bits) {
  return __uint_as_float((bits >> 9) | 0x3f800000u) - 1.0f;
}

__device__ inline float sigm_fast(float x) { return 1.0f / (1.0f + __expf(-x)); }

// XLA fp32 ErfInv polynomial
__device__ inline float erfinv_f32(float x) {
  float w = -log1pf(-x * x);
  float p;
  if (w < 5.0f) {
    w -= 2.5f;
    p = 2.81022636e-08f;
    p = fmaf(p, w, 3.43273939e-07f);
    p = fmaf(p, w, -3.5233877e-06f);
    p = fmaf(p, w, -4.39150654e-06f);
    p = fmaf(p, w, 0.00021858087f);
    p = fmaf(p, w, -0.00125372503f);
    p = fmaf(p, w, -0.00417768164f);
    p = fmaf(p, w, 0.246640727f);
    p = fmaf(p, w, 1.50140941f);
  } else {
    w = sqrtf(w) - 3.0f;
    p = -0.000200214257f;
    p = fmaf(p, w, 0.000100950558f);
    p = fmaf(p, w, 0.00134934322f);
    p = fmaf(p, w, -0.00367342844f);
    p = fmaf(p, w, 0.00573950773f);
    p = fmaf(p, w, -0.0076224613f);
    p = fmaf(p, w, 0.00943887047f);
    p = fmaf(p, w, 1.00167406f);
    p = fmaf(p, w, 2.83297682f);
  }
  return p * x;
}

// Full MDN head for one (m,t) row; lane = component. yg/ysg/ym are this lane's
// gamma-logit / log-sigma / mu. Writes 2 floats (lane 0).
__device__ inline void mdn_head(float yg, float ysg, float ym, int lane, uint32_t rid,
                                uint32_t k1a, uint32_t k1b, uint32_t k2a, uint32_t k2b,
                                float* __restrict__ out) {
  // Gumbel-argmax categorical
  uint32_t pp = rid * (uint32_t)NCdim + (uint32_t)lane;
  uint32_t bits = random_bits32(k1a, k1b, pp);
  float u01 = bits_to_u01(bits);
  const float tinyf = 1.17549435e-38f;
  float uu = fmaxf(tinyf, u01 + tinyf);
  float gum = -logf(-logf(uu));
  float val = gum + yg;
  int idx = lane;
#pragma unroll
  for (int s = 1; s < 64; s <<= 1) {
    float ov = __shfl_xor(val, s);
    int oi = __shfl_xor(idx, s);
    if (ov > val || (ov == val && oi < idx)) { val = ov; idx = oi; }
  }
  float mu_sel = __shfl(ym, idx);
  float s_sel = __shfl(ysg, idx);

  uint32_t ebits = random_bits32(k2a, k2b, rid);
  float ue = bits_to_u01(ebits);
  const float lo = __uint_as_float(0xBF7FFFFFu);  // nextafter(-1, 0)
  float un = fmaxf(lo, ue * 2.0f + lo);
  float eps = 1.41421356f * erfinv_f32(un);

  float x_pred = mu_sel + expf(s_sel) * eps;

  // x_cond_prob in log domain
  float mx = yg;
#pragma unroll
  for (int s = 1; s < 64; s <<= 1) mx = fmaxf(mx, __shfl_xor(mx, s));
  float se = expf(yg - mx);
#pragma unroll
  for (int s = 1; s < 64; s <<= 1) se += __shfl_xor(se, s);
  float d = x_pred - ym;
  float lk = -0.5f * d * d - 66.0f * ysg - 58.812066f;
  float ts = expf(yg - mx + lk);
#pragma unroll
  for (int s = 1; s < 64; s <<= 1) ts += __shfl_xor(ts, s);
  float prob = ts / se;

  if (lane == 0) {
    out[rid] = x_pred;
    out[(size_t)Mdim * Tdim + rid] = prob;
  }
}

__global__ void vfpg_prep(const float* __restrict__ Wih0, const float* __restrict__ Whh0,
                          const float* __restrict__ Wih1, const float* __restrict__ Whh1,
                          const float* __restrict__ fcW, const float* __restrict__ bih0,
                          const float* __restrict__ bhh0, const float* __restrict__ bih1,
                          const float* __restrict__ bhh1, float* __restrict__ ws) {
  int i0 = blockIdx.x * blockDim.x + threadIdx.x;
  int n = blockDim.x * gridDim.x;
  float4* wz = (float4*)(ws + OFF_WZ0P);
  for (int o = i0; o < 8 * 512; o += n) {
    int kz = o >> 9, tt = o & 511, uu = tt >> 1, pp = tt & 1;
    int g1 = pp * 512 + uu, g2 = g1 + 256;
    wz[o] = make_float4(Wih0[g1 * INdim + 2 * kz], Wih0[g2 * INdim + 2 * kz],
                        Wih0[g1 * INdim + 2 * kz + 1], Wih0[g2 * INdim + 2 * kz + 1]);
  }
  float4* wh = (float4*)(ws + OFF_WH0P);
  for (int o = i0; o < 128 * 512; o += n) {
    int k2 = o >> 9, tt = o & 511, uu = tt >> 1, pp = tt & 1;
    int g1 = pp * 512 + uu, g2 = g1 + 256;
    wh[o] = make_float4(Whh0[g1 * Hdim + 2 * k2], Whh0[g2 * Hdim + 2 * k2],
                        Whh0[g1 * Hdim + 2 * k2 + 1], Whh0[g2 * Hdim + 2 * k2 + 1]);
  }
  float4* w1 = (float4*)(ws + OFF_W1P);
  for (int o = i0; o < 256 * 512; o += n) {
    int k = o >> 9, tt = o & 511, uu = tt >> 1, pp = tt & 1;
    int g1 = pp * 512 + uu, g2 = g1 + 256;
    w1[o] = make_float4(Wih1[g1 * Hdim + k], Wih1[g2 * Hdim + k],
                        Whh1[g1 * Hdim + k], Whh1[g2 * Hdim + k]);
  }
  float4* wfcp = (float4*)(ws + OFF_WFCP);
  for (int o = i0; o < 256 * 64; o += n) {
    int k = o >> 6, c = o & 63;
    wfcp[o] = make_float4(fcW[c * Hdim + k], fcW[(64 + c) * Hdim + k],
                          fcW[(128 + c) * Hdim + k], 0.0f);
  }
  float2* b0 = (float2*)(ws + OFF_BG0);
  float2* b1 = (float2*)(ws + OFF_BG1);
  for (int o = i0; o < 512; o += n) {
    int uu = o >> 1, pp = o & 1;
    int g1 = pp * 512 + uu, g2 = g1 + 256;
    b0[o] = make_float2(bih0[g1] + bhh0[g1], bih0[g2] + bhh0[g2]);
    b1[o] = make_float2(bih1[g1] + bhh1[g1], bih1[g2] + bhh1[g2]);
  }
}

// SPLIT=1: stream h1 to h1g, no FC/MDN in-loop. SPLIT=0: fused FC/MDN phase C.
template <int SPLIT>
__launch_bounds__(NTHREADS, 1)
__global__ void vfpg_rec(const float* __restrict__ z, const float* __restrict__ ws,
                         const float* __restrict__ fcb, float* __restrict__ out,
                         float* __restrict__ h1g,
                         uint32_t k1a, uint32_t k1b, uint32_t k2a, uint32_t k2b) {
  __shared__ __align__(16) float h0s[2][RROWS][Hdim];  // 16 KB
  __shared__ __align__(16) float h1s[2][RROWS][Hdim];  // 16 KB
  __shared__ __align__(16) float zsb[2][RROWS][INdim]; // 1 KB

  const int tid = threadIdx.x;
  const int u = tid >> 1;
  const int p = tid & 1;
  const int lane = tid & 63;
  const int wid = tid >> 6;
  const int m0 = blockIdx.x * RROWS;

  const float4* WZ = (const float4*)(ws + OFF_WZ0P);
  const float4* WH = (const float4*)(ws + OFF_WH0P);
  const float4* W1 = (const float4*)(ws + OFF_W1P);
  const float4* WFCP = (const float4*)(ws + OFF_WFCP);
  const float2 bg0 = ((const float2*)(ws + OFF_BG0))[tid];
  const float2 bg1 = ((const float2*)(ws + OFF_BG1))[tid];
  float fbg = 0.f, fbs = 0.f, fbm = 0.f;
  if (!SPLIT) { fbg = fcb[lane]; fbs = fcb[64 + lane]; fbm = fcb[128 + lane]; }

  const float4* WHp = WH + tid;   // stride 512 float4 per k-row
  const float4* W1p = W1 + tid;

  float c0[4] = {0.f, 0.f, 0.f, 0.f};
  float c1[4] = {0.f, 0.f, 0.f, 0.f};

  for (int i = tid; i < RROWS * Hdim; i += NTHREADS) {
    (&h0s[1][0][0])[i] = 0.0f;
    (&h1s[1][0][0])[i] = 0.0f;
  }
  if (tid < RROWS * INdim) {
    int r = tid >> 4, f = tid & 15;
    zsb[0][r][f] = z[(size_t)(m0 + r) * (Tdim * INdim) + f];
  }
  __syncthreads();

#pragma unroll 1
  for (int t = 0; t < Tdim; t++) {
    const int cur = t & 1, prv = cur ^ 1;

    // ============ Phase A: layer-0 gates + cell update ============
    {
      float a[8], b[8];
#pragma unroll
      for (int r = 0; r < 8; r++) { a[r] = bg0.x; b[r] = bg0.y; }
      // z contribution (k = 0..15)
#pragma unroll
      for (int kz = 0; kz < 8; kz++) {
        float4 w = WZ[kz * 512 + tid];
#pragma unroll
        for (int r = 0; r < 8; r++) {
          float2 zz = *(const float2*)&zsb[cur][r][2 * kz];
          a[r] = fmaf(zz.x, w.x, a[r]);
          b[r] = fmaf(zz.x, w.y, b[r]);
          a[r] = fmaf(zz.y, w.z, a[r]);
          b[r] = fmaf(zz.y, w.w, b[r]);
        }
      }
      // recurrent contribution, manual 1-deep register prefetch
      float4 w0 = WHp[0], w1v = WHp[512];
#pragma unroll 2
      for (int k4 = 0; k4 < 64; k4++) {
        // over-reads 1 row into W1P region at k4=63: in-bounds, discarded
        float4 n0 = WHp[(2 * k4 + 2) * 512];
        float4 n1 = WHp[(2 * k4 + 3) * 512];
#pragma unroll
        for (int r = 0; r < 8; r++) {
          float4 h4 = *(const float4*)&h0s[prv][r][4 * k4];
          a[r] = fmaf(h4.x, w0.x, a[r]);
          b[r] = fmaf(h4.x, w0.y, b[r]);
          a[r] = fmaf(h4.y, w0.z, a[r]);
          b[r] = fmaf(h4.y, w0.w, b[r]);
          a[r] = fmaf(h4.z, w1v.x, a[r]);
          b[r] = fmaf(h4.z, w1v.y, b[r]);
          a[r] = fmaf(h4.w, w1v.z, a[r]);
          b[r] = fmaf(h4.w, w1v.w, b[r]);
        }
        w0 = n0; w1v = n1;
      }
      // update: p=0 holds (i,f), p=1 holds (g,o). tanh(x) = 2*sigm(2x)-1.
      float sa[8], sb[8];
#pragma unroll
      for (int r = 0; r < 8; r++) {
        float xa = p ? 2.0f * a[r] : a[r];
        float s = sigm_fast(xa);
        sa[r] = p ? fmaf(2.0f, s, -1.0f) : s;
        sb[r] = sigm_fast(b[r]);
      }
#pragma unroll
      for (int j = 0; j < 4; j++) {
        float s1 = __shfl_xor(p ? sa[j] : sa[j + 4], 1);
        float s2 = __shfl_xor(p ? sb[j] : sb[j + 4], 1);
        float own_a = p ? sa[j + 4] : sa[j];
        float own_b = p ? sb[j + 4] : sb[j];
        float si = p ? s1 : own_a;
        float sf = p ? s2 : own_b;
        float tg = p ? own_a : s1;
        float so = p ? own_b : s2;
        c0[j] = sf * c0[j] + si * tg;
        float th = fmaf(2.0f, sigm_fast(2.0f * c0[j]), -1.0f);
        h0s[cur][p * 4 + j][u] = so * th;
      }
    }
    __syncthreads();

    // ============ Phase B: layer-1 gates + cell update + z stage ============
    {
      // stage next z early (hides latency under the GEMM)
      if (t + 1 < Tdim && tid < RROWS * INdim) {
        int r = tid >> 4, f = tid & 15;
        zsb[prv][r][f] = z[(size_t)(m0 + r) * (Tdim * INdim) + (t + 1) * INdim + f];
      }
      float a[8], b[8];
#pragma unroll
      for (int r = 0; r < 8; r++) { a[r] = bg1.x; b[r] = bg1.y; }
      float4 w0 = W1p[0], w1v = W1p[512], w2 = W1p[1024], w3 = W1p[1536];
#pragma unroll 2
      for (int k4 = 0; k4 < 64; k4++) {
        // over-reads 4 rows into WFCP region at k4=63: in-bounds, discarded
        float4 n0 = W1p[(4 * k4 + 4) * 512];
        float4 n1 = W1p[(4 * k4 + 5) * 512];
        float4 n2 = W1p[(4 * k4 + 6) * 512];
        float4 n3 = W1p[(4 * k4 + 7) * 512];
#pragma unroll
        for (int r = 0; r < 8; r++) {
          float4 x = *(const float4*)&h0s[cur][r][4 * k4];
          float4 y = *(const float4*)&h1s[prv][r][4 * k4];
          a[r] = fmaf(x.x, w0.x, a[r]);
          b[r] = fmaf(x.x, w0.y, b[r]);
          a[r] = fmaf(y.x, w0.z, a[r]);
          b[r] = fmaf(y.x, w0.w, b[r]);
          a[r] = fmaf(x.y, w1v.x, a[r]);
          b[r] = fmaf(x.y, w1v.y, b[r]);
          a[r] = fmaf(y.y, w1v.z, a[r]);
          b[r] = fmaf(y.y, w1v.w, b[r]);
          a[r] = fmaf(x.z, w2.x, a[r]);
          b[r] = fmaf(x.z, w2.y, b[r]);
          a[r] = fmaf(y.z, w2.z, a[r]);
          b[r] = fmaf(y.z, w2.w, b[r]);
          a[r] = fmaf(x.w, w3.x, a[r]);
          b[r] = fmaf(x.w, w3.y, b[r]);
          a[r] = fmaf(y.w, w3.z, a[r]);
          b[r] = fmaf(y.w, w3.w, b[r]);
        }
        w0 = n0; w1v = n1; w2 = n2; w3 = n3;
      }
      float sa[8], sb[8];
#pragma unroll
      for (int r = 0; r < 8; r++) {
        float xa = p ? 2.0f * a[r] : a[r];
        float s = sigm_fast(xa);
        sa[r] = p ? fmaf(2.0f, s, -1.0f) : s;
        sb[r] = sigm_fast(b[r]);
      }
#pragma unroll
      for (int j = 0; j < 4; j++) {
        float s1 = __shfl_xor(p ? sa[j] : sa[j + 4], 1);
        float s2 = __shfl_xor(p ? sb[j] : sb[j + 4], 1);
        float own_a = p ? sa[j + 4] : sa[j];
        float own_b = p ? sb[j + 4] : sb[j];
        float si = p ? s1 : own_a;
        float sf = p ? s2 : own_b;
        float tg = p ? own_a : s1;
        float so = p ? own_b : s2;
        c1[j] = sf * c1[j] + si * tg;
        float th = fmaf(2.0f, sigm_fast(2.0f * c1[j]), -1.0f);
        h1s[cur][p * 4 + j][u] = so * th;
      }
    }
    __syncthreads();

    if (SPLIT) {
      // coalesced h1 -> global (read of h1s[cur]; next write to this buffer is B(t+2))
      const int sr = tid >> 6;
      const int sc = (tid & 63) * 4;
      float4 hv = *(const float4*)&h1s[cur][sr][sc];
      *(float4*)&h1g[((size_t)(m0 + sr) * Tdim + t) * Hdim + sc] = hv;
    } else {
      // ============ Phase C: FC + MDN head (wave w -> row w) ============
      const int r = wid;
      const uint32_t rid = (uint32_t)(m0 + r) * Tdim + (uint32_t)t;
      float yg = fbg, ysg = fbs, ym = fbm;
#pragma unroll 2
      for (int k4 = 0; k4 < 64; k4++) {
        float4 h4 = *(const float4*)&h1s[cur][r][4 * k4];
#pragma unroll
        for (int j = 0; j < 4; j++) {
          float4 w = WFCP[(4 * k4 + j) * 64 + lane];
          float hv = (&h4.x)[j];
          yg = fmaf(hv, w.x, yg);
          ysg = fmaf(hv, w.y, ysg);
          ym = fmaf(hv, w.z, ym);
        }
      }
      mdn_head(yg, ysg, ym, lane, rid, k1a, k1b, k2a, k2b, out);
      __syncthreads();
    }
  }
}

// Pass 2 (SPLIT): FC + MDN head for all M*T rows; wave -> one row.
__launch_bounds__(NTHREADS, 1)
__global__ void vfpg_head(const float* __restrict__ ws, const float* __restrict__ h1g,
                          const float* __restrict__ fcb, float* __restrict__ out,
                          uint32_t k1a, uint32_t k1b, uint32_t k2a, uint32_t k2b) {
  __shared__ __align__(16) float hs[NTHREADS / 64][Hdim];  // 8 KB
  const int lane = threadIdx.x & 63;
  const int wid = threadIdx.x >> 6;
  const uint32_t rid = (uint32_t)(blockIdx.x * (NTHREADS / 64) + wid);  // m*T + t

  const float4* WFCP = (const float4*)(ws + OFF_WFCP);

  // stage this row's h into LDS
  float4 hv = *(const float4*)&h1g[(size_t)rid * Hdim + 4 * lane];
  *(float4*)&hs[wid][4 * lane] = hv;
  __builtin_amdgcn_s_waitcnt(0);  // lgkmcnt(0)+vmcnt(0) conservative: wave-local LDS visibility
  float yg = fcb[lane], ysg = fcb[64 + lane], ym = fcb[128 + lane];
#pragma unroll 2
  for (int k4 = 0; k4 < 64; k4++) {
    float4 h4 = *(const float4*)&hs[wid][4 * k4];
#pragma unroll
    for (int j = 0; j < 4; j++) {
      float4 w = WFCP[(4 * k4 + j) * 64 + lane];
      float hh = (&h4.x)[j];
      yg = fmaf(hh, w.x, yg);
      ysg = fmaf(hh, w.y, ysg);
      ym = fmaf(hh, w.z, ym);
    }
  }
  mdn_head(yg, ysg, ym, lane, rid, k1a, k1b, k2a, k2b, out);
}

extern "C" void kernel_launch(void* const* d_in, const int* in_sizes, int n_in,
                              void* d_out, int out_size, void* d_ws, size_t ws_size,
                              hipStream_t stream) {
  const float* z    = (const float*)d_in[0];
  const float* Wih0 = (const float*)d_in[1];
  const float* Whh0 = (const float*)d_in[2];
  const float* bih0 = (const float*)d_in[3];
  const float* bhh0 = (const float*)d_in[4];
  const float* Wih1 = (const float*)d_in[5];
  const float* Whh1 = (const float*)d_in[6];
  const float* bih1 = (const float*)d_in[7];
  const float* bhh1 = (const float*)d_in[8];
  const float* fcW  = (const float*)d_in[9];
  const float* fcb  = (const float*)d_in[10];
  float* ws = (float*)d_ws;
  float* out = (float*)d_out;

  if (ws_size < (size_t)WS_FUSED * sizeof(float)) return;
  const bool split = ws_size >= (size_t)WS_SPLIT * sizeof(float);

  vfpg_prep<<<dim3(512), dim3(256), 0, stream>>>(
      Wih0, Whh0, Wih1, Whh1, fcW, bih0, bhh0, bih1, bhh1, ws);

  uint32_t k1a, k1b, k2a, k2b;
  tf2x32(0u, 42u, 0u, 0u, &k1a, &k1b);
  tf2x32(0u, 42u, 0u, 1u, &k2a, &k2b);

  if (split) {
    float* h1g = ws + OFF_H1;
    vfpg_rec<1><<<dim3(NBLK), dim3(NTHREADS), 0, stream>>>(
        z, ws, fcb, out, h1g, k1a, k1b, k2a, k2b);
    vfpg_head<<<dim3(Mdim * Tdim / (NTHREADS / 64)), dim3(NTHREADS), 0, stream>>>(
        ws, h1g, fcb, out, k1a, k1b, k2a, k2b);
  } else {
    vfpg_rec<0><<<dim3(NBLK), dim3(NTHREADS), 0, stream>>>(
        z, ws, fcb, out, nullptr, k1a, k1b, k2a, k2b);
  }
}